// Round 5
// baseline (299.191 us; speedup 1.0000x reference)
//
#include <hip/hip_runtime.h>
#include <hip/hip_bf16.h>

#define NN 50000
#define NPAD 53248              // 13 * 4096, scan padding
#define EE 800000
#define EHALF 400128            // 1563*256 — edges counted in K1; rest in K2
#define DIM 256
#define NEG_SLOPE 0.2f
#define LOG2E 1.44269504088896f

#define GEMM_BLOCKS 1564        // 391 * 4
#define CNTA_BLOCKS 1563        // EHALF/256
#define CNTB_BLOCKS 1562        // (EE-EHALF)/256
#define FILL_BLOCKS 3125
#define CVT_BLOCKS  12500
#define WT_BLOCKS   512

typedef __attribute__((ext_vector_type(8))) short short8;
typedef __attribute__((ext_vector_type(4))) float f32x4;
typedef __attribute__((ext_vector_type(2))) float v2f;

__device__ __forceinline__ unsigned short f2bf(float f) {
    unsigned u = __float_as_uint(f);
    unsigned r = (u + 0x7fffu + ((u >> 16) & 1u)) >> 16;   // RNE
    return (unsigned short)r;
}
__device__ __forceinline__ float u2f_lo(unsigned u) {      // bf16 in low 16
    return __uint_as_float(u << 16);
}
__device__ __forceinline__ float u2f_hi(unsigned u) {      // bf16 in high 16
    return __uint_as_float(u & 0xffff0000u);
}

// 8-lane sum via DPP (VALU pipe only — no ds_swizzle LDS round trips).
__device__ __forceinline__ float red8(float s) {
    int t;
    t = __builtin_amdgcn_update_dpp(0, __float_as_int(s), 0xB1, 0xF, 0xF, true);
    s += __int_as_float(t);
    t = __builtin_amdgcn_update_dpp(0, __float_as_int(s), 0x4E, 0xF, 0xF, true);
    s += __int_as_float(t);
    t = __builtin_amdgcn_update_dpp(0, __float_as_int(s), 0x141, 0xF, 0xF, true);
    s += __int_as_float(t);
    return s;
}

// ---------------------------------------------------------------------------
// K1: blocks [0,1563) count FIRST HALF of edges (atomic-latency-bound)
// overlapped with [1563,14063) x->bf16 cvt and [14063,14575) Wt build.
// Second half of the count runs inside K2, hidden under the GEMM (separate
// VMEM-latency vs MFMA pipes overlap). Rank only needs per-dst uniqueness,
// not arrival order — softmax/accum are order-invariant up to fp32 rounding.
// ---------------------------------------------------------------------------
__global__ __launch_bounds__(256) void k_prep(
    const float* __restrict__ x, const float* __restrict__ Wl,
    const float* __restrict__ Wr, const int* __restrict__ ei,
    unsigned short* __restrict__ xb, unsigned short* __restrict__ wt,
    int* __restrict__ cnt, int* __restrict__ rank)
{
    int b = blockIdx.x;
    if (b < CNTA_BLOCKS) {                                 // count edges [0,EHALF)
        int e = b * 256 + threadIdx.x;
        int dst = ei[EE + e];
        rank[e] = atomicAdd(&cnt[dst], 1);
    } else if (b < CNTA_BLOCKS + CVT_BLOCKS) {             // x -> bf16
        int i = ((b - CNTA_BLOCKS) * 256 + threadIdx.x) * 4;
        float4 v = *(const float4*)(x + i);
        ushort4 o;
        o.x = f2bf(v.x); o.y = f2bf(v.y); o.z = f2bf(v.z); o.w = f2bf(v.w);
        *(ushort4*)(xb + i) = o;
    } else {                                               // Wt build
        int idx = (b - CNTA_BLOCKS - CVT_BLOCKS) * 256 + threadIdx.x;
        int n = idx >> 8, k = idx & 255;
        float v = (n < 256) ? Wl[k * 256 + n] : Wr[k * 256 + (n - 256)];
        wt[idx] = f2bf(v);
    }
}

// ---------------------------------------------------------------------------
// K2 (fused): blocks [0,1564) MFMA GEMM {xl,xr} = xb @ [Wl|Wr]^T with
// bijective chunked XCD swizzle; blocks [1564,3126) count SECOND HALF of
// edges — atomic latency hides under co-resident MFMA waves.
// Epilogue v5: C staged through LDS ([64][136] bf16, 2 rounds) so global
// stores are 16B dwordx4 (16x fewer store instructions than 2B scalar).
// ---------------------------------------------------------------------------
__global__ __launch_bounds__(256) void k_cnt_gemm(
    const unsigned short* __restrict__ xb, const unsigned short* __restrict__ wt,
    const int* __restrict__ ei, int* __restrict__ cnt, int* __restrict__ rank,
    unsigned short* __restrict__ xl, unsigned short* __restrict__ xr)
{
    __shared__ short sAB[8704];      // main: A[0,4096) B[4096,8192); epi: [64][136]
    int tid = threadIdx.x;

    if (blockIdx.x >= GEMM_BLOCKS) {            // ---- count edges [EHALF,EE) ----
        int e = EHALF + (blockIdx.x - GEMM_BLOCKS) * 256 + tid;
        int dst = ei[EE + e];
        rank[e] = atomicAdd(&cnt[dst], 1);
        return;
    }

    // ---- GEMM ----
    // bijective chunked XCD swizzle: orig id = kk*8+xcd -> chunk(xcd) + kk
    int bid = blockIdx.x;
    const int q = GEMM_BLOCKS / 8, r = GEMM_BLOCKS % 8;     // 195, 4
    int xcd = bid & 7, kk = bid >> 3;
    int wg = (xcd < r) ? xcd * (q + 1) + kk
                       : r * (q + 1) + (xcd - r) * q + kk;

    int wid = tid >> 6, lane = tid & 63;
    int mt = wg >> 2, nt = wg & 3;
    int mBase = mt * 128, nBase = nt * 128;
    int wm = (wid & 1) * 64, wn = (wid >> 1) * 64;
    int qq4 = lane >> 4, mh = lane & 15;

    f32x4 acc[4][4];
#pragma unroll
    for (int i = 0; i < 4; ++i)
#pragma unroll
        for (int j = 0; j < 4; ++j)
            acc[i][j] = (f32x4){0.f, 0.f, 0.f, 0.f};

    int aoff[4], boff[4];
#pragma unroll
    for (int f = 0; f < 4; ++f) {
        int rr = wm + f * 16 + mh;
        aoff[f] = (rr * 4 + (qq4 ^ (rr & 3))) * 8;
        int nl = wn + f * 16 + mh;
        boff[f] = 4096 + (nl * 4 + (qq4 ^ (nl & 3))) * 8;
    }

    for (int k0 = 0; k0 < 256; k0 += 32) {
        __syncthreads();
#pragma unroll
        for (int it = 0; it < 4; ++it) {
            int L = it * 256 + tid;
            const unsigned short* g;
            if (L < 512) {
                int rr = L >> 2;
                int q2 = (L & 3) ^ (rr & 3);
                int grow = mBase + rr;
                if (grow > NN - 1) grow = NN - 1;
                g = xb + (size_t)grow * 256 + k0 + q2 * 8;
            } else {
                int LB = L - 512;
                int nl = LB >> 2;
                int q2 = (LB & 3) ^ (nl & 3);
                g = wt + (size_t)(nBase + nl) * 256 + k0 + q2 * 8;
            }
            short* lp = sAB + (it * 256 + wid * 64) * 8;
            __builtin_amdgcn_global_load_lds(
                (const __attribute__((address_space(1))) void*)g,
                (__attribute__((address_space(3))) void*)lp, 16, 0, 0);
        }
        __syncthreads();

        short8 af[4], bfr[4];
#pragma unroll
        for (int f = 0; f < 4; ++f) af[f]  = *(const short8*)(sAB + aoff[f]);
#pragma unroll
        for (int f = 0; f < 4; ++f) bfr[f] = *(const short8*)(sAB + boff[f]);
#pragma unroll
        for (int i = 0; i < 4; ++i)
#pragma unroll
            for (int j = 0; j < 4; ++j)
                acc[i][j] = __builtin_amdgcn_mfma_f32_16x16x32_bf16(
                    af[i], bfr[j], acc[i][j], 0, 0, 0);
    }

    // ---- epilogue: LDS-staged coalesced C-write ----
    // round t stages rows [t*64, t*64+64) of the 128x128 tile in LDS
    // (stride 136 shorts: banks spread, 2-way max on b128 reads), then all
    // 4 waves store 16B dwordx4 chunks. nt<2 -> xl, nt>=2 -> xr.
    unsigned short* cb = (nt < 2) ? xl : xr;
    int chalf = (nt & 1) * 128;
#pragma unroll
    for (int t = 0; t < 2; ++t) {
        __syncthreads();                     // previous LDS readers done
        if ((wid & 1) == t) {                // waves owning rows [t*64, t*64+64)
#pragma unroll
            for (int i = 0; i < 4; ++i)
#pragma unroll
                for (int j = 0; j < 4; ++j)
#pragma unroll
                    for (int rr = 0; rr < 4; ++rr) {
                        int lrow = i * 16 + qq4 * 4 + rr;
                        int lcol = wn + j * 16 + mh;
                        sAB[lrow * 136 + lcol] = (short)f2bf(acc[i][j][rr]);
                    }
        }
        __syncthreads();
        int row = tid >> 2, seg = tid & 3;
        int grow = mBase + t * 64 + row;
        if (grow < NN) {
            const short* lp = sAB + row * 136 + seg * 32;
            short8 v0 = *(const short8*)(lp);
            short8 v1 = *(const short8*)(lp + 8);
            short8 v2 = *(const short8*)(lp + 16);
            short8 v3 = *(const short8*)(lp + 24);
            unsigned short* gp = cb + (size_t)grow * 256 + chalf + seg * 32;
            *(short8*)(gp)      = v0;
            *(short8*)(gp + 8)  = v1;
            *(short8*)(gp + 16) = v2;
            *(short8*)(gp + 24) = v3;
        }
    }
}

// ---------------------------------------------------------------------------
// K3: exclusive prefix sum of cnt -> row_start (int4-vectorized, 1 block).
// ---------------------------------------------------------------------------
__global__ __launch_bounds__(1024) void k_scan(
    const int* __restrict__ cnt, int* __restrict__ row_start)
{
    __shared__ int wsum[16];
    int tid = threadIdx.x, lane = tid & 63, wid = tid >> 6;
    int4 v[13];
#pragma unroll
    for (int p = 0; p < 13; ++p)
        v[p] = *(const int4*)(cnt + p * 4096 + tid * 4);
    int carry = 0;
#pragma unroll
    for (int p = 0; p < 13; ++p) {
        int4 vv = v[p];
        int tsum = vv.x + vv.y + vv.z + vv.w;
        int s = tsum;
#pragma unroll
        for (int off = 1; off < 64; off <<= 1) {
            int t = __shfl_up(s, off, 64);
            if (lane >= off) s += t;
        }
        if (lane == 63) wsum[wid] = s;
        __syncthreads();
        int wpre = 0, tot = 0;
#pragma unroll
        for (int w = 0; w < 16; ++w) {
            int xv = wsum[w];
            tot += xv;
            if (w < wid) wpre += xv;
        }
        int ex = carry + wpre + (s - tsum);
        int4 o;
        o.x = ex;
        o.y = o.x + vv.x;
        o.z = o.y + vv.y;
        o.w = o.z + vv.z;
        *(int4*)(row_start + p * 4096 + tid * 4) = o;
        carry += tot;
        __syncthreads();
    }
}

// ---------------------------------------------------------------------------
// K4: CSR fill (scattered-write-bound, NO atomics). 3125*256 == EE exactly.
// ---------------------------------------------------------------------------
__global__ __launch_bounds__(256) void k_fill(
    const int* __restrict__ ei, const float* __restrict__ ea,
    const int* __restrict__ row_start, const int* __restrict__ rank,
    uint2* __restrict__ edge_rec)
{
    int e = blockIdx.x * 256 + threadIdx.x;
    int src = ei[e];
    int dst = ei[EE + e];
    float2 a = *(const float2*)(ea + 2 * e);
    int pos = row_start[dst] + rank[e];
    unsigned packed = ((unsigned)f2bf(a.y) << 16) | f2bf(a.x);
    edge_rec[pos] = make_uint2((unsigned)src, packed);
}

// ---------------------------------------------------------------------------
// K5: fused attention — one wave per dst node (unchanged from round 4:
// chunk-cached edge records + readlane, group-of-4 register-renamed gather
// pipeline, DPP 8-lane reduction, packed-fp32 math). Control group this round.
// ---------------------------------------------------------------------------
__global__ __launch_bounds__(256) void k_attn(
    const unsigned short* __restrict__ xl, const unsigned short* __restrict__ xr,
    const int* __restrict__ row_start, const uint2* __restrict__ edge_rec,
    const float* __restrict__ W_e, const float* __restrict__ att,
    const float* __restrict__ bias, float* __restrict__ out)
{
    int n = __builtin_amdgcn_readfirstlane(blockIdx.x * 4 + (threadIdx.x >> 6));
    if (n >= NN) return;
    int lane = threadIdx.x & 63;
    int j = lane * 4;

    uint2 xru = *(const uint2*)(xr + ((size_t)n << 8) + j);
    v2f xr01 = {u2f_lo(xru.x), u2f_hi(xru.x)};
    v2f xr23 = {u2f_lo(xru.y), u2f_hi(xru.y)};
    float4 av = *(const float4*)(att + j);
    v2f att01 = {av.x * LOG2E, av.y * LOG2E};
    v2f att23 = {av.z * LOG2E, av.w * LOG2E};
    float4 w0v = *(const float4*)(W_e + j);
    float4 w1v = *(const float4*)(W_e + 256 + j);
    v2f we0_01 = {w0v.x, w0v.y}, we0_23 = {w0v.z, w0v.w};
    v2f we1_01 = {w1v.x, w1v.y}, we1_23 = {w1v.z, w1v.w};
    const v2f sl2 = {NEG_SLOPE, NEG_SLOPE};

    int rs = __builtin_amdgcn_readfirstlane(row_start[n]);
    int cn = __builtin_amdgcn_readfirstlane(row_start[n + 1]) - rs;

    float D = 0.0f, la0 = 0.0f, la1 = 0.0f;
    v2f acc01 = {0.f, 0.f}, acc23 = {0.f, 0.f};

    auto body = [&](uint2 ru, float a0, float a1) {
        v2f xl01 = {u2f_lo(ru.x), u2f_hi(ru.x)};
        v2f xl23 = {u2f_lo(ru.y), u2f_hi(ru.y)};
        v2f a0v = {a0, a0}, a1v = {a1, a1};
        v2f m01 = xl01 + xr01;
        v2f m23 = xl23 + xr23;
        m01 = __builtin_elementwise_fma(a0v, we0_01, m01);
        m23 = __builtin_elementwise_fma(a0v, we0_23, m23);
        m01 = __builtin_elementwise_fma(a1v, we1_01, m01);
        m23 = __builtin_elementwise_fma(a1v, we1_23, m23);
        v2f t01 = __builtin_elementwise_max(m01, m01 * sl2);
        v2f t23 = __builtin_elementwise_max(m23, m23 * sl2);
        v2f sv = t01 * att01;
        sv = __builtin_elementwise_fma(t23, att23, sv);
        float s = sv.x + sv.y;
        s = red8(s);
        float w = __builtin_amdgcn_exp2f(s);
        D += w;
        v2f wv = {w, w};
        acc01 = __builtin_elementwise_fma(wv, xl01, acc01);
        acc23 = __builtin_elementwise_fma(wv, xl23, acc23);
    };

    int done = 0;
    while (done < cn) {
        int m = cn - done; if (m > 64) m = 64;
        int ridx = rs + done + lane;
        if (ridx > EE + 63) ridx = EE + 63;          // zeroed pad region
        uint2 rc = edge_rec[ridx];
        int rcx = (int)rc.x, rca = (int)rc.y;

        auto gat = [&](int k) -> uint2 {             // k is wave-uniform
            unsigned sidx = (unsigned)__builtin_amdgcn_readlane(rcx, k);
            return *(const uint2*)(xl + ((size_t)sidx << 8) + j);
        };
        auto proc = [&](uint2 xu, int k) {
            unsigned pk = (unsigned)__builtin_amdgcn_readlane(rca, k);
            float a0 = __uint_as_float(pk << 16);
            float a1 = __uint_as_float(pk & 0xffff0000u);
            la0 += a0; la1 += a1;
            body(xu, a0, a1);
        };

        uint2 x0 = gat(0), x1 = gat(1), x2 = gat(2), x3 = gat(3);
        for (int i = 0; i < m; i += 4) {
            proc(x0, i);
            if (i + 4 < m) x0 = gat(i + 4);
            if (i + 1 < m) { proc(x1, i + 1); if (i + 5 < m) x1 = gat(i + 5); }
            if (i + 2 < m) { proc(x2, i + 2); if (i + 6 < m) x2 = gat(i + 6); }
            if (i + 3 < m) { proc(x3, i + 3); if (i + 7 < m) x3 = gat(i + 7); }
        }
        done += m;
    }

    // self loop last, with mean edge attr of incoming edges
    float invc = 1.0f / fmaxf((float)cn, 1.0f);
    uint2 xs = *(const uint2*)(xl + ((size_t)n << 8) + j);
    body(xs, la0 * invc, la1 * invc);

    float invD = 1.0f / D;
    float4 b4 = *(const float4*)(bias + j);
    float4 o;
    o.x = fmaf(acc01.x, invD, b4.x);
    o.y = fmaf(acc01.y, invD, b4.y);
    o.z = fmaf(acc23.x, invD, b4.z);
    o.w = fmaf(acc23.y, invD, b4.w);
    *(float4*)(out + (size_t)n * 256 + j) = o;
}

// ---------------------------------------------------------------------------
extern "C" void kernel_launch(void* const* d_in, const int* in_sizes, int n_in,
                              void* d_out, int out_size, void* d_ws, size_t ws_size,
                              hipStream_t stream)
{
    const float* x    = (const float*)d_in[0];
    const int*   ei   = (const int*)  d_in[1];
    const float* ea   = (const float*)d_in[2];
    const float* Wl   = (const float*)d_in[3];
    const float* Wr   = (const float*)d_in[4];
    const float* We   = (const float*)d_in[5];
    const float* att  = (const float*)d_in[6];
    const float* bias = (const float*)d_in[7];
    float* out = (float*)d_out;

    char* ws = (char*)d_ws;
    size_t off = 0;
    unsigned short* xl = (unsigned short*)(ws + off); off += (size_t)NN * 256 * 2;   // 25.6 MB
    unsigned short* xr = (unsigned short*)(ws + off); off += (size_t)NN * 256 * 2;   // 25.6 MB
    unsigned short* xb = (unsigned short*)(ws + off); off += (size_t)NN * 256 * 2;   // 25.6 MB
    uint2*  edge_rec   = (uint2*)(ws + off);          off += (size_t)(EE + 64) * 8;  //  6.4 MB (+512B pad)
    int*    cnt        = (int*)(ws + off);            off += (size_t)NPAD * 4;       //  (adjacent to pad!)
    int*    row_st     = (int*)(ws + off);            off += (size_t)NPAD * 4;
    int*    rank       = (int*)(ws + off);            off += (size_t)EE * 4;         //  3.2 MB
    unsigned short* wt = (unsigned short*)(ws + off); off += (size_t)512 * 256 * 2;  // 256 KB
    // total ~87 MB

    // single memset zeroes the edge_rec prefetch pad AND cnt (adjacent)
    hipMemsetAsync(edge_rec + EE, 0, 64 * sizeof(uint2) + NPAD * sizeof(int), stream);

    k_prep    <<<CNTA_BLOCKS + CVT_BLOCKS + WT_BLOCKS, 256, 0, stream>>>(
        x, Wl, Wr, ei, xb, wt, cnt, rank);
    k_cnt_gemm<<<GEMM_BLOCKS + CNTB_BLOCKS, 256, 0, stream>>>(
        xb, wt, ei, cnt, rank, xl, xr);
    k_scan    <<<1, 1024, 0, stream>>>(cnt, row_st);
    k_fill    <<<FILL_BLOCKS, 256, 0, stream>>>(
        ei, ea, row_st, rank, edge_rec);
    k_attn    <<<12500, 256, 0, stream>>>(
        xl, xr, row_st, edge_rec, We, att, bias, out);
}

// Round 6
// 258.707 us; speedup vs baseline: 1.1565x; 1.1565x over previous
//
#include <hip/hip_runtime.h>
#include <hip/hip_bf16.h>

#define NN 50000
#define NPAD 53248              // 13 * 4096, scan padding
#define EE 800000
#define DIM 256
#define NEG_SLOPE 0.2f
#define LOG2E 1.44269504088896f

#define GEMM_BLOCKS 1564        // 391 * 4
#define FILL_BLOCKS 3125
#define MIX_BLOCKS  15625       // 3125 count + 12500 cvt, interleaved 1:4
#define WT_BLOCKS   512

typedef __attribute__((ext_vector_type(8))) short short8;
typedef __attribute__((ext_vector_type(4))) float f32x4;
typedef __attribute__((ext_vector_type(2))) float v2f;

__device__ __forceinline__ unsigned short f2bf(float f) {
    unsigned u = __float_as_uint(f);
    unsigned r = (u + 0x7fffu + ((u >> 16) & 1u)) >> 16;   // RNE
    return (unsigned short)r;
}
__device__ __forceinline__ float u2f_lo(unsigned u) {      // bf16 in low 16
    return __uint_as_float(u << 16);
}
__device__ __forceinline__ float u2f_hi(unsigned u) {      // bf16 in high 16
    return __uint_as_float(u & 0xffff0000u);
}

// 8-lane sum via DPP (VALU pipe only — no ds_swizzle LDS round trips).
__device__ __forceinline__ float red8(float s) {
    int t;
    t = __builtin_amdgcn_update_dpp(0, __float_as_int(s), 0xB1, 0xF, 0xF, true);
    s += __int_as_float(t);
    t = __builtin_amdgcn_update_dpp(0, __float_as_int(s), 0x4E, 0xF, 0xF, true);
    s += __int_as_float(t);
    t = __builtin_amdgcn_update_dpp(0, __float_as_int(s), 0x141, 0xF, 0xF, true);
    s += __int_as_float(t);
    return s;
}

// ---------------------------------------------------------------------------
// K1: degree count + per-edge rank (atomic-latency-bound) INTERLEAVED 1:4
// with x->bf16 cvt blocks (HBM-bound) so the atomic storm never owns the
// whole machine; Wt build at the tail. cnt zeroed by preceding memset.
// Rank only needs per-dst uniqueness, not arrival order.
// ---------------------------------------------------------------------------
__global__ __launch_bounds__(256) void k_prep_count(
    const float* __restrict__ x, const float* __restrict__ Wl,
    const float* __restrict__ Wr, const int* __restrict__ ei,
    unsigned short* __restrict__ xb, unsigned short* __restrict__ wt,
    int* __restrict__ cnt, int* __restrict__ rank)
{
    int b = blockIdx.x;
    if (b < MIX_BLOCKS) {
        int g = b / 5;
        if (b - g * 5 == 0) {                              // count role (1 in 5)
            int e = g * 256 + threadIdx.x;                 // g in [0,3125)
            int dst = ei[EE + e];
            rank[e] = atomicAdd(&cnt[dst], 1);
        } else {                                           // cvt role (4 in 5)
            int ci = b - g - 1;                            // [0,12500)
            int i = (ci * 256 + threadIdx.x) * 4;
            float4 v = *(const float4*)(x + i);
            ushort4 o;
            o.x = f2bf(v.x); o.y = f2bf(v.y); o.z = f2bf(v.z); o.w = f2bf(v.w);
            *(ushort4*)(xb + i) = o;
        }
    } else {                                               // Wt build
        int idx = (b - MIX_BLOCKS) * 256 + threadIdx.x;
        int n = idx >> 8, k = idx & 255;
        float v = (n < 256) ? Wl[k * 256 + n] : Wr[k * 256 + (n - 256)];
        wt[idx] = f2bf(v);
    }
}

// ---------------------------------------------------------------------------
// K2: exclusive prefix sum of cnt -> row_start (int4-vectorized, 1 block).
// ---------------------------------------------------------------------------
__global__ __launch_bounds__(1024) void k_scan(
    const int* __restrict__ cnt, int* __restrict__ row_start)
{
    __shared__ int wsum[16];
    int tid = threadIdx.x, lane = tid & 63, wid = tid >> 6;
    int4 v[13];
#pragma unroll
    for (int p = 0; p < 13; ++p)
        v[p] = *(const int4*)(cnt + p * 4096 + tid * 4);
    int carry = 0;
#pragma unroll
    for (int p = 0; p < 13; ++p) {
        int4 vv = v[p];
        int tsum = vv.x + vv.y + vv.z + vv.w;
        int s = tsum;
#pragma unroll
        for (int off = 1; off < 64; off <<= 1) {
            int t = __shfl_up(s, off, 64);
            if (lane >= off) s += t;
        }
        if (lane == 63) wsum[wid] = s;
        __syncthreads();
        int wpre = 0, tot = 0;
#pragma unroll
        for (int w = 0; w < 16; ++w) {
            int xv = wsum[w];
            tot += xv;
            if (w < wid) wpre += xv;
        }
        int ex = carry + wpre + (s - tsum);
        int4 o;
        o.x = ex;
        o.y = o.x + vv.x;
        o.z = o.y + vv.y;
        o.w = o.z + vv.z;
        *(int4*)(row_start + p * 4096 + tid * 4) = o;
        carry += tot;
        __syncthreads();
    }
}

// ---------------------------------------------------------------------------
// K3 (fused): blocks [0,1564) MFMA GEMM {xl,xr} = xb @ [Wl|Wr]^T
// overlapped with [1564,4689) CSR fill (scattered-write-bound, NO atomics).
// Bijective chunked XCD swizzle (verified: FETCH 14.5MB in round-5 PMC).
// C written split: cols [0,256) -> xl, [256,512) -> xr.  (round-4 verified)
// ---------------------------------------------------------------------------
__global__ __launch_bounds__(256) void k_gemm_fill(
    const unsigned short* __restrict__ xb, const unsigned short* __restrict__ wt,
    const int* __restrict__ ei, const float* __restrict__ ea,
    const int* __restrict__ row_start, const int* __restrict__ rank,
    unsigned short* __restrict__ xl, unsigned short* __restrict__ xr,
    uint2* __restrict__ edge_rec)
{
    __shared__ short sAB[8192];                 // A: [0,4096) B: [4096,8192)
    int tid = threadIdx.x;

    if (blockIdx.x >= GEMM_BLOCKS) {            // ---- CSR fill ----
        int e = (blockIdx.x - GEMM_BLOCKS) * 256 + tid;
        if (e < EE) {
            int src = ei[e];
            int dst = ei[EE + e];
            float2 a = *(const float2*)(ea + 2 * e);
            int pos = row_start[dst] + rank[e];
            unsigned packed = ((unsigned)f2bf(a.y) << 16) | f2bf(a.x);
            edge_rec[pos] = make_uint2((unsigned)src, packed);
        }
        return;
    }

    // ---- GEMM ----
    // bijective chunked XCD swizzle: orig id = kk*8+xcd -> chunk(xcd) + kk
    int bid = blockIdx.x;
    const int q = GEMM_BLOCKS / 8, r = GEMM_BLOCKS % 8;     // 195, 4
    int xcd = bid & 7, kk = bid >> 3;
    int wg = (xcd < r) ? xcd * (q + 1) + kk
                       : r * (q + 1) + (xcd - r) * q + kk;

    int wid = tid >> 6, lane = tid & 63;
    int mt = wg >> 2, nt = wg & 3;
    int mBase = mt * 128, nBase = nt * 128;
    int wm = (wid & 1) * 64, wn = (wid >> 1) * 64;
    int qq4 = lane >> 4, mh = lane & 15;

    f32x4 acc[4][4];
#pragma unroll
    for (int i = 0; i < 4; ++i)
#pragma unroll
        for (int j = 0; j < 4; ++j)
            acc[i][j] = (f32x4){0.f, 0.f, 0.f, 0.f};

    int aoff[4], boff[4];
#pragma unroll
    for (int f = 0; f < 4; ++f) {
        int rr = wm + f * 16 + mh;
        aoff[f] = (rr * 4 + (qq4 ^ (rr & 3))) * 8;
        int nl = wn + f * 16 + mh;
        boff[f] = 4096 + (nl * 4 + (qq4 ^ (nl & 3))) * 8;
    }

    for (int k0 = 0; k0 < 256; k0 += 32) {
        __syncthreads();
#pragma unroll
        for (int it = 0; it < 4; ++it) {
            int L = it * 256 + tid;
            const unsigned short* g;
            if (L < 512) {
                int rr = L >> 2;
                int q2 = (L & 3) ^ (rr & 3);
                int grow = mBase + rr;
                if (grow > NN - 1) grow = NN - 1;
                g = xb + (size_t)grow * 256 + k0 + q2 * 8;
            } else {
                int LB = L - 512;
                int nl = LB >> 2;
                int q2 = (LB & 3) ^ (nl & 3);
                g = wt + (size_t)(nBase + nl) * 256 + k0 + q2 * 8;
            }
            short* lp = sAB + (it * 256 + wid * 64) * 8;
            __builtin_amdgcn_global_load_lds(
                (const __attribute__((address_space(1))) void*)g,
                (__attribute__((address_space(3))) void*)lp, 16, 0, 0);
        }
        __syncthreads();

        short8 af[4], bfr[4];
#pragma unroll
        for (int f = 0; f < 4; ++f) af[f]  = *(const short8*)(sAB + aoff[f]);
#pragma unroll
        for (int f = 0; f < 4; ++f) bfr[f] = *(const short8*)(sAB + boff[f]);
#pragma unroll
        for (int i = 0; i < 4; ++i)
#pragma unroll
            for (int j = 0; j < 4; ++j)
                acc[i][j] = __builtin_amdgcn_mfma_f32_16x16x32_bf16(
                    af[i], bfr[j], acc[i][j], 0, 0, 0);
    }

    // split C-write: nt<2 -> xl, nt>=2 -> xr; col-in-half = (nt&1)*128 + ...
    unsigned short* cb = (nt < 2) ? xl : xr;
    int chalf = (nt & 1) * 128;
#pragma unroll
    for (int i = 0; i < 4; ++i)
#pragma unroll
        for (int j = 0; j < 4; ++j)
#pragma unroll
            for (int rr = 0; rr < 4; ++rr) {
                int row = mBase + wm + i * 16 + qq4 * 4 + rr;
                if (row < NN) {
                    int col = chalf + wn + j * 16 + mh;
                    cb[(size_t)row * 256 + col] = f2bf(acc[i][j][rr]);
                }
            }
}

// ---------------------------------------------------------------------------
// K5: fused attention — one wave per dst node.
// v6: gather ring deepened 4 -> 8 (covers ~720cy of gather latency vs ~90cy
// of per-edge VALU; round-2's flat result showed the marginal bound is
// latency, not issue). Chunk-cached edge records + readlane, DPP reduction,
// packed-fp32 math. edge_rec pad covers prologue over-gathers.
// ---------------------------------------------------------------------------
__global__ __launch_bounds__(256) void k_attn(
    const unsigned short* __restrict__ xl, const unsigned short* __restrict__ xr,
    const int* __restrict__ row_start, const uint2* __restrict__ edge_rec,
    const float* __restrict__ W_e, const float* __restrict__ att,
    const float* __restrict__ bias, float* __restrict__ out)
{
    int n = __builtin_amdgcn_readfirstlane(blockIdx.x * 4 + (threadIdx.x >> 6));
    if (n >= NN) return;
    int lane = threadIdx.x & 63;
    int j = lane * 4;

    uint2 xru = *(const uint2*)(xr + ((size_t)n << 8) + j);
    v2f xr01 = {u2f_lo(xru.x), u2f_hi(xru.x)};
    v2f xr23 = {u2f_lo(xru.y), u2f_hi(xru.y)};
    float4 av = *(const float4*)(att + j);
    v2f att01 = {av.x * LOG2E, av.y * LOG2E};
    v2f att23 = {av.z * LOG2E, av.w * LOG2E};
    float4 w0v = *(const float4*)(W_e + j);
    float4 w1v = *(const float4*)(W_e + 256 + j);
    v2f we0_01 = {w0v.x, w0v.y}, we0_23 = {w0v.z, w0v.w};
    v2f we1_01 = {w1v.x, w1v.y}, we1_23 = {w1v.z, w1v.w};
    const v2f sl2 = {NEG_SLOPE, NEG_SLOPE};

    int rs = __builtin_amdgcn_readfirstlane(row_start[n]);
    int cn = __builtin_amdgcn_readfirstlane(row_start[n + 1]) - rs;

    float D = 0.0f, la0 = 0.0f, la1 = 0.0f;
    v2f acc01 = {0.f, 0.f}, acc23 = {0.f, 0.f};

    auto body = [&](uint2 ru, float a0, float a1) {
        v2f xl01 = {u2f_lo(ru.x), u2f_hi(ru.x)};
        v2f xl23 = {u2f_lo(ru.y), u2f_hi(ru.y)};
        v2f a0v = {a0, a0}, a1v = {a1, a1};
        v2f m01 = xl01 + xr01;
        v2f m23 = xl23 + xr23;
        m01 = __builtin_elementwise_fma(a0v, we0_01, m01);
        m23 = __builtin_elementwise_fma(a0v, we0_23, m23);
        m01 = __builtin_elementwise_fma(a1v, we1_01, m01);
        m23 = __builtin_elementwise_fma(a1v, we1_23, m23);
        v2f t01 = __builtin_elementwise_max(m01, m01 * sl2);
        v2f t23 = __builtin_elementwise_max(m23, m23 * sl2);
        v2f sv = t01 * att01;
        sv = __builtin_elementwise_fma(t23, att23, sv);
        float s = sv.x + sv.y;
        s = red8(s);
        float w = __builtin_amdgcn_exp2f(s);
        D += w;
        v2f wv = {w, w};
        acc01 = __builtin_elementwise_fma(wv, xl01, acc01);
        acc23 = __builtin_elementwise_fma(wv, xl23, acc23);
    };

    int done = 0;
    while (done < cn) {
        int m = cn - done; if (m > 64) m = 64;
        int ridx = rs + done + lane;
        if (ridx > EE + 63) ridx = EE + 63;          // zeroed pad region
        uint2 rc = edge_rec[ridx];
        int rcx = (int)rc.x, rca = (int)rc.y;

        auto gat = [&](int k) -> uint2 {             // k is wave-uniform
            unsigned sidx = (unsigned)__builtin_amdgcn_readlane(rcx, k);
            return *(const uint2*)(xl + ((size_t)sidx << 8) + j);
        };
        auto proc = [&](uint2 xu, int k) {
            unsigned pk = (unsigned)__builtin_amdgcn_readlane(rca, k);
            float a0 = __uint_as_float(pk << 16);
            float a1 = __uint_as_float(pk & 0xffff0000u);
            la0 += a0; la1 += a1;
            body(xu, a0, a1);
        };

        uint2 x0 = gat(0), x1 = gat(1), x2 = gat(2), x3 = gat(3);
        uint2 x4 = gat(4), x5 = gat(5), x6 = gat(6), x7 = gat(7);
        for (int i = 0; i < m; i += 8) {
            proc(x0, i);
            if (i +  8 < m) x0 = gat(i +  8);
            if (i + 1 < m) { proc(x1, i + 1); if (i +  9 < m) x1 = gat(i +  9); }
            if (i + 2 < m) { proc(x2, i + 2); if (i + 10 < m) x2 = gat(i + 10); }
            if (i + 3 < m) { proc(x3, i + 3); if (i + 11 < m) x3 = gat(i + 11); }
            if (i + 4 < m) { proc(x4, i + 4); if (i + 12 < m) x4 = gat(i + 12); }
            if (i + 5 < m) { proc(x5, i + 5); if (i + 13 < m) x5 = gat(i + 13); }
            if (i + 6 < m) { proc(x6, i + 6); if (i + 14 < m) x6 = gat(i + 14); }
            if (i + 7 < m) { proc(x7, i + 7); if (i + 15 < m) x7 = gat(i + 15); }
        }
        done += m;
    }

    // self loop last, with mean edge attr of incoming edges
    float invc = 1.0f / fmaxf((float)cn, 1.0f);
    uint2 xs = *(const uint2*)(xl + ((size_t)n << 8) + j);
    body(xs, la0 * invc, la1 * invc);

    float invD = 1.0f / D;
    float4 b4 = *(const float4*)(bias + j);
    float4 o;
    o.x = fmaf(acc01.x, invD, b4.x);
    o.y = fmaf(acc01.y, invD, b4.y);
    o.z = fmaf(acc23.x, invD, b4.z);
    o.w = fmaf(acc23.y, invD, b4.w);
    *(float4*)(out + (size_t)n * 256 + j) = o;
}

// ---------------------------------------------------------------------------
extern "C" void kernel_launch(void* const* d_in, const int* in_sizes, int n_in,
                              void* d_out, int out_size, void* d_ws, size_t ws_size,
                              hipStream_t stream)
{
    const float* x    = (const float*)d_in[0];
    const int*   ei   = (const int*)  d_in[1];
    const float* ea   = (const float*)d_in[2];
    const float* Wl   = (const float*)d_in[3];
    const float* Wr   = (const float*)d_in[4];
    const float* We   = (const float*)d_in[5];
    const float* att  = (const float*)d_in[6];
    const float* bias = (const float*)d_in[7];
    float* out = (float*)d_out;

    char* ws = (char*)d_ws;
    size_t off = 0;
    unsigned short* xl = (unsigned short*)(ws + off); off += (size_t)NN * 256 * 2;   // 25.6 MB
    unsigned short* xr = (unsigned short*)(ws + off); off += (size_t)NN * 256 * 2;   // 25.6 MB
    unsigned short* xb = (unsigned short*)(ws + off); off += (size_t)NN * 256 * 2;   // 25.6 MB
    uint2*  edge_rec   = (uint2*)(ws + off);          off += (size_t)(EE + 64) * 8;  //  6.4 MB (+512B pad)
    int*    cnt        = (int*)(ws + off);            off += (size_t)NPAD * 4;       //  (adjacent to pad!)
    int*    row_st     = (int*)(ws + off);            off += (size_t)NPAD * 4;
    int*    rank       = (int*)(ws + off);            off += (size_t)EE * 4;         //  3.2 MB
    unsigned short* wt = (unsigned short*)(ws + off); off += (size_t)512 * 256 * 2;  // 256 KB
    // total ~87 MB

    // single memset zeroes the edge_rec prefetch pad AND cnt (adjacent)
    hipMemsetAsync(edge_rec + EE, 0, 64 * sizeof(uint2) + NPAD * sizeof(int), stream);

    k_prep_count<<<MIX_BLOCKS + WT_BLOCKS, 256, 0, stream>>>(
        x, Wl, Wr, ei, xb, wt, cnt, rank);
    k_scan      <<<1, 1024, 0, stream>>>(cnt, row_st);
    k_gemm_fill <<<GEMM_BLOCKS + FILL_BLOCKS, 256, 0, stream>>>(
        xb, wt, ei, ea, row_st, rank, xl, xr, edge_rec);
    k_attn      <<<12500, 256, 0, stream>>>(
        xl, xr, row_st, edge_rec, We, att, bias, out);
}